// Round 6
// baseline (301.396 us; speedup 1.0000x reference)
//
#include <hip/hip_runtime.h>
#include <hip/hip_bf16.h>

typedef __attribute__((ext_vector_type(8))) short short8;   // 8 x bf16 (4 VGPRs)
typedef __attribute__((ext_vector_type(4))) float floatx4;  // MFMA acc
typedef __attribute__((ext_vector_type(2))) float floatx2;  // packed f32 (v_pk_*_f32)

#define XS_STRIDE 72    // ushorts; xs[136][72] = 19584 B at smem+0, DEAD after A2a reg-preload
#define PXN 136         // staged pixels: 4 rows x 34 (h=2 tile + halo)
#define QBASE 17424     // Q region at 17408+16: +16 staggers Q bank quads by 1 vs P
// LDS map (34,832 B total -> 4 blocks/CU, 139,328 <= 163,840):
//   P region [136][128B] at 0      : chunk g = channels g*16..+7 (bf16), overlays xs
//   Q region [136][128B] at 17424  : chunk g = channels g*16+8..+15
//   chunk swizzle: physical 16B-chunk = logical ^ (px & 7)
// Phase B is BARRIER-FREE: direct per-channel stores; 4 waves complete each 128B
// output line in L2 (verified round 5: WRITE_SIZE == output size exactly).

__device__ __forceinline__ ushort f2bf(float f) {
    union { __hip_bfloat16 h; ushort u; } cv;
    cv.h = __float2bfloat16(f);
    return cv.u;
}
__device__ __forceinline__ float bflo(unsigned int u) { return __uint_as_float(u << 16); }
__device__ __forceinline__ float bfhi(unsigned int u) { return __uint_as_float(u & 0xffff0000u); }
__device__ __forceinline__ floatx2 bf2f2(unsigned int u) {
    floatx2 r; r.x = __uint_as_float(u << 16); r.y = __uint_as_float(u & 0xffff0000u); return r;
}
// packed PV accumulate: 4 x v_pk_fma_f32 per uint4 (8 channels)
__device__ __forceinline__ void fmaacc(uint4 p, floatx2 a2, floatx2* o2) {
    o2[0] += a2 * bf2f2(p.x); o2[1] += a2 * bf2f2(p.y);
    o2[2] += a2 * bf2f2(p.z); o2[3] += a2 * bf2f2(p.w);
}

// 8-lane (same-pixel) reduce: xor1/xor2 on VALU via DPP quad_perm, xor4 via shfl.
__device__ __forceinline__ float gsum8(float v) {
    v += __int_as_float(__builtin_amdgcn_update_dpp(0, __float_as_int(v), 0xB1, 0xF, 0xF, false)); // xor1
    v += __int_as_float(__builtin_amdgcn_update_dpp(0, __float_as_int(v), 0x4E, 0xF, 0xF, false)); // xor2
    v += __shfl_xor(v, 4);                                                                          // xor4
    return v;
}

// ---- phase-B building blocks (macros: compile-time slot indices -> registers) ----
#define LOADROW(S, PROW)                                                            \
    {                                                                               \
        _Pragma("unroll")                                                           \
        for (int dx = 0; dx < 3; ++dx) {                                            \
            int pi = (PROW) * 34 + ox + dx;                                         \
            const char* pp = smc + pi * 128 + ((g * 16) ^ ((pi & 7) << 4));         \
            wlo[S][dx] = *(const uint4*)pp;                                         \
            whi[S][dx] = *(const uint4*)(pp + QBASE);                               \
        }                                                                           \
    }

#define SCORE1(S, DX) ({                                                            \
        uint4 _l = wlo[S][DX], _h = whi[S][DX];                                     \
        floatx2 _s = bf2f2(_l.x) * cf2[0];                                          \
        _s += bf2f2(_l.y) * cf2[1];                                                 \
        _s += bf2f2(_l.z) * cf2[2];                                                 \
        _s += bf2f2(_l.w) * cf2[3];                                                 \
        _s += bf2f2(_h.x) * cf2[4];                                                 \
        _s += bf2f2(_h.y) * cf2[5];                                                 \
        _s += bf2f2(_h.z) * cf2[6];                                                 \
        _s += bf2f2(_h.w) * cf2[7];                                                 \
        _s.x + _s.y; })

#define PV(S, DX, A)                                                                \
    {                                                                               \
        floatx2 _a2; _a2.x = (A); _a2.y = (A);                                      \
        fmaacc(wlo[S][DX], _a2, o2);                                                \
        fmaacc(whi[S][DX], _a2, o2 + 4);                                            \
    }

#define ATTN_OY(OY, ST, SM, SB)                                                     \
    {                                                                               \
        floatx2 cf2[8];                                                             \
        {                                                                           \
            uint4 c0 = wlo[SM][1], c1 = whi[SM][1];                                 \
            cf2[0] = bf2f2(c0.x); cf2[1] = bf2f2(c0.y);                             \
            cf2[2] = bf2f2(c0.z); cf2[3] = bf2f2(c0.w);                             \
            cf2[4] = bf2f2(c1.x); cf2[5] = bf2f2(c1.y);                             \
            cf2[6] = bf2f2(c1.z); cf2[7] = bf2f2(c1.w);                             \
        }                                                                           \
        float s[9];                                                                 \
        s[0] = SCORE1(ST, 0); s[1] = SCORE1(ST, 1); s[2] = SCORE1(ST, 2);           \
        s[3] = SCORE1(SM, 0); s[4] = SCORE1(SM, 1); s[5] = SCORE1(SM, 2);           \
        s[6] = SCORE1(SB, 0); s[7] = SCORE1(SB, 1); s[8] = SCORE1(SB, 2);           \
        _Pragma("unroll")                                                           \
        for (int n = 0; n < 9; ++n)                                                 \
            s[n] = gsum8(s[n]) * 0.08838834764831845f;  /* 1/sqrt(128) */           \
        float m = s[0];                                                             \
        _Pragma("unroll")                                                           \
        for (int n = 1; n < 9; ++n) m = fmaxf(m, s[n]);                             \
        float e[9], sum = 0.f;                                                      \
        _Pragma("unroll")                                                           \
        for (int n = 0; n < 9; ++n) { e[n] = __expf(s[n] - m); sum += e[n]; }       \
        floatx2 o2[8];                                                              \
        _Pragma("unroll")                                                           \
        for (int k = 0; k < 8; ++k) { o2[k].x = 0.f; o2[k].y = 0.f; }               \
        PV(ST, 0, e[0]) PV(ST, 1, e[1]) PV(ST, 2, e[2])                             \
        PV(SM, 0, e[3]) PV(SM, 1, e[4]) PV(SM, 2, e[5])                             \
        PV(SB, 0, e[6]) PV(SB, 1, e[7]) PV(SB, 2, e[8])                             \
        float inv = 1.f / sum;                                                      \
        floatx2 inv2; inv2.x = inv; inv2.y = inv;                                   \
        float* og = out + ((size_t)((b * 128 + g * 16) * 128 + (h0 + (OY)))) * 128  \
                    + w0 + ox;                                                      \
        _Pragma("unroll")                                                           \
        for (int k = 0; k < 8; ++k) {                                               \
            floatx2 v = o2[k] * inv2;                                               \
            og[(2 * k) * 16384]     = v.x;                                          \
            og[(2 * k + 1) * 16384] = v.y;                                          \
        }                                                                           \
    }

__global__ __launch_bounds__(256, 4)
void attn_conv_fused(const float* __restrict__ x, const float* __restrict__ Wc,
                     const float* __restrict__ bc, float* __restrict__ out) {
    __shared__ __align__(16) unsigned char smem[34832];
    ushort* xs = (ushort*)smem;
    char* smc = (char*)smem;

    const int tid = threadIdx.x;
    // XCD-chunked swizzle (bijective, 2048 = 8*256): XCD k owns batch k entirely;
    // within an XCD, w-tiles fastest then h-bands -> halo rows stay L2-resident.
    const int rid = ((blockIdx.x & 7) << 8) | (blockIdx.x >> 3);
    const int b   = rid >> 8;
    const int h0  = ((rid >> 2) & 63) * 2;
    const int w0  = (rid & 3) * 32;
    const int lane = tid & 63;
    const int wv   = tid >> 6;

    // ---------------- Phase A0: stage x tile transposed -> xs[px][ci] bf16 ----
    if (tid < PXN) {
        int py  = (tid * 965) >> 15;          // tid / 34 (exact for tid<208)
        int pxx = tid - py * 34;
        int gh = h0 + py - 1, gw = w0 + pxx - 1;
        bool inb = (gh >= 0 && gh < 128 && gw >= 0 && gw < 128);
        ushort* dst = xs + tid * XS_STRIDE;
        if (inb) {
            const float* xp = x + (b * 64) * 16384 + gh * 128 + gw;
            #pragma unroll
            for (int c0 = 0; c0 < 64; c0 += 4) {
                float v0 = xp[(c0 + 0) << 14];
                float v1 = xp[(c0 + 1) << 14];
                float v2 = xp[(c0 + 2) << 14];
                float v3 = xp[(c0 + 3) << 14];
                unsigned int u01 = (unsigned int)f2bf(v0) | ((unsigned int)f2bf(v1) << 16);
                unsigned int u23 = (unsigned int)f2bf(v2) | ((unsigned int)f2bf(v3) << 16);
                *(uint2*)(dst + c0) = make_uint2(u01, u23);
            }
        } else {
            #pragma unroll
            for (int c0 = 0; c0 < 64; c0 += 4)
                *(uint2*)(dst + c0) = make_uint2(0u, 0u);
        }
    }

    // ---------------- Phase A1: W fragments (B-operand) from global ----------
    const int col = lane & 15;
    const int kq  = lane >> 4;
    short8 bw[8][2];
    float  bias[8];
    #pragma unroll
    for (int t = 0; t < 8; ++t) {
        int c = t * 16 + col;
        bias[t] = bc[c];
        #pragma unroll
        for (int half = 0; half < 2; ++half) {
            const float* wp = Wc + c * 64 + half * 32 + kq * 8;
            float4 wa = *(const float4*)wp;
            float4 wb = *(const float4*)(wp + 4);
            short8 f;
            f[0] = (short)f2bf(wa.x); f[1] = (short)f2bf(wa.y);
            f[2] = (short)f2bf(wa.z); f[3] = (short)f2bf(wa.w);
            f[4] = (short)f2bf(wb.x); f[5] = (short)f2bf(wb.y);
            f[6] = (short)f2bf(wb.z); f[7] = (short)f2bf(wb.w);
            bw[t][half] = f;
        }
    }
    __syncthreads();

    // ---------------- Phase A2a: preload this wave's A-fragments (xs dies) ----
    // 9 m-tiles (144 >= 136) over 4 waves: wave wv handles mt = wv, wv+4, wv+8
    short8 af0[3], af1[3];
    #pragma unroll
    for (int i = 0; i < 3; ++i) {
        int mt = wv + i * 4;
        if (mt < 9) {
            const ushort* ap = xs + (mt * 16 + col) * XS_STRIDE + kq * 8;
            af0[i] = *(const short8*)(ap);        // k 0..31  (px>=136 reads junk; masked on write)
            af1[i] = *(const short8*)(ap + 32);   // k 32..63
        }
    }
    __syncthreads();   // all xs reads done; P/Q (overlaying xs) now writable

    // ---------------- Phase A2b: MFMA conv -> P/Q bf16 (swizzled) ------------
    // channel c = t*16+col -> region (col<8 ? P : Q), chunk t ^ (pxr&7), slot col&7
    char* wbase = smc + (col < 8 ? 0 : QBASE);
    const int cb2 = (col & 7) * 2;
    #pragma unroll
    for (int i = 0; i < 3; ++i) {
        int mt = wv + i * 4;
        if (mt < 9) {
            floatx4 acc[8];
            #pragma unroll
            for (int t = 0; t < 8; ++t) acc[t] = (floatx4){0.f, 0.f, 0.f, 0.f};
            #pragma unroll
            for (int t = 0; t < 8; ++t) {
                acc[t] = __builtin_amdgcn_mfma_f32_16x16x32_bf16(af0[i], bw[t][0], acc[t], 0, 0, 0);
                acc[t] = __builtin_amdgcn_mfma_f32_16x16x32_bf16(af1[i], bw[t][1], acc[t], 0, 0, 0);
            }
            #pragma unroll
            for (int r = 0; r < 4; ++r) {
                int pxr = mt * 16 + kq * 4 + r;   // D row = (lane>>4)*4 + r
                if (pxr < PXN) {
                    int py  = (pxr * 965) >> 15;
                    int pxx = pxr - py * 34;
                    int gh = h0 + py - 1, gw = w0 + pxx - 1;
                    bool inb = (gh >= 0 && gh < 128 && gw >= 0 && gw < 128);
                    char* prow = wbase + pxr * 128;
                    int swz = (pxr & 7) << 4;
                    #pragma unroll
                    for (int t = 0; t < 8; ++t)
                        *(ushort*)(prow + (((t * 16) ^ swz) + cb2)) =
                            f2bf(inb ? (acc[t][r] + bias[t]) : 0.f);
                }
            }
        }
    }
    __syncthreads();   // LAST barrier: phase B is read-only on LDS, fully async

    // ---------------- Phase B: 3x3 local attention, barrier-free -------------
    // thread (g, ox): channels g*16..+15, pixel column ox; patch window carried
    // in registers across oy (rows oy..oy+2 of padded tile; reuse 2 of 3 rows).
    const int g  = tid & 7;                   // channel group: c0 = g*16
    const int ox = tid >> 3;                  // 0..31
    uint4 wlo[3][3], whi[3][3];               // [row slot][dx], lo=P chunk, hi=Q chunk

    LOADROW(0, 0) LOADROW(1, 1) LOADROW(2, 2)
    ATTN_OY(0, 0, 1, 2)
    LOADROW(0, 3)
    ATTN_OY(1, 1, 2, 0)
}

extern "C" void kernel_launch(void* const* d_in, const int* in_sizes, int n_in,
                              void* d_out, int out_size, void* d_ws, size_t ws_size,
                              hipStream_t stream) {
    const float* x  = (const float*)d_in[0];
    const float* Wc = (const float*)d_in[1];
    const float* bc = (const float*)d_in[2];
    float* out = (float*)d_out;

    dim3 grid(2048);         // flat; XCD-chunked decode in-kernel (h=2, w=32 tiles)
    dim3 block(256);
    attn_conv_fused<<<grid, block, 0, stream>>>(x, Wc, bc, out);
}

// Round 7
// 142.560 us; speedup vs baseline: 2.1142x; 2.1142x over previous
//
#include <hip/hip_runtime.h>
#include <hip/hip_bf16.h>

typedef __attribute__((ext_vector_type(8))) short short8;   // 8 x bf16 (4 VGPRs)
typedef __attribute__((ext_vector_type(4))) float floatx4;  // MFMA acc
typedef __attribute__((ext_vector_type(2))) float floatx2;  // packed f32 (v_pk_*_f32)

#define XS_STRIDE 72    // ushorts; xs[136][72] = 19584 B at smem+0, DEAD after A2a reg-preload
#define PXN 136         // staged pixels: 4 rows x 34 (h=2 tile + halo)
#define QBASE 17424     // Q region at 17408+16: +16 staggers Q bank quads by 1 vs P
// LDS map (34,832 B total -> 4 blocks/CU at VGPR<=128):
//   P region [136][128B] at 0      : chunk g = channels g*16..+7 (bf16), overlays xs
//   Q region [136][128B] at 17424  : chunk g = channels g*16+8..+15
//   chunk swizzle: physical 16B-chunk = logical ^ (px & 7)
// Phase B is BARRIER-FREE: direct per-channel stores; waves complete each 128B
// output line in L2 (verified round 5: WRITE_SIZE == output size exactly).
// LAUNCH BOUNDS NOTE (measured rounds 3-6): 2nd arg 2 -> VGPR cap 128 (round 3 hit
// exactly 128); 2nd arg 3 -> cap ~84; 2nd arg 4 -> cap 64 (round 6: total spill,
// 446 MB scratch writes). (256,2) is the unique setting giving 4 waves/SIMD
// WITHOUT forcing spills. Do not raise the 2nd arg.

__device__ __forceinline__ ushort f2bf(float f) {
    union { __hip_bfloat16 h; ushort u; } cv;
    cv.h = __float2bfloat16(f);
    return cv.u;
}
__device__ __forceinline__ float bflo(unsigned int u) { return __uint_as_float(u << 16); }
__device__ __forceinline__ float bfhi(unsigned int u) { return __uint_as_float(u & 0xffff0000u); }
__device__ __forceinline__ floatx2 bf2f2(unsigned int u) {
    floatx2 r; r.x = __uint_as_float(u << 16); r.y = __uint_as_float(u & 0xffff0000u); return r;
}
// packed PV accumulate: 4 x v_pk_fma_f32 per uint4 (8 channels)
__device__ __forceinline__ void fmaacc(uint4 p, floatx2 a2, floatx2* o2) {
    o2[0] += a2 * bf2f2(p.x); o2[1] += a2 * bf2f2(p.y);
    o2[2] += a2 * bf2f2(p.z); o2[3] += a2 * bf2f2(p.w);
}

// 8-lane (same-pixel) reduce: xor1/xor2 on VALU via DPP quad_perm, xor4 via shfl.
__device__ __forceinline__ float gsum8(float v) {
    v += __int_as_float(__builtin_amdgcn_update_dpp(0, __float_as_int(v), 0xB1, 0xF, 0xF, false)); // xor1
    v += __int_as_float(__builtin_amdgcn_update_dpp(0, __float_as_int(v), 0x4E, 0xF, 0xF, false)); // xor2
    v += __shfl_xor(v, 4);                                                                          // xor4
    return v;
}

// ---- phase-B building blocks (macros: compile-time slot indices -> registers) ----
#define LOADROW(S, PROW)                                                            \
    {                                                                               \
        _Pragma("unroll")                                                           \
        for (int dx = 0; dx < 3; ++dx) {                                            \
            int pi = (PROW) * 34 + ox + dx;                                         \
            const char* pp = smc + pi * 128 + ((g * 16) ^ ((pi & 7) << 4));         \
            wlo[S][dx] = *(const uint4*)pp;                                         \
            whi[S][dx] = *(const uint4*)(pp + QBASE);                               \
        }                                                                           \
    }

#define SCORE1(S, DX) ({                                                            \
        uint4 _l = wlo[S][DX], _h = whi[S][DX];                                     \
        floatx2 _s = bf2f2(_l.x) * cf2[0];                                          \
        _s += bf2f2(_l.y) * cf2[1];                                                 \
        _s += bf2f2(_l.z) * cf2[2];                                                 \
        _s += bf2f2(_l.w) * cf2[3];                                                 \
        _s += bf2f2(_h.x) * cf2[4];                                                 \
        _s += bf2f2(_h.y) * cf2[5];                                                 \
        _s += bf2f2(_h.z) * cf2[6];                                                 \
        _s += bf2f2(_h.w) * cf2[7];                                                 \
        _s.x + _s.y; })

#define PV(S, DX, A)                                                                \
    {                                                                               \
        floatx2 _a2; _a2.x = (A); _a2.y = (A);                                      \
        fmaacc(wlo[S][DX], _a2, o2);                                                \
        fmaacc(whi[S][DX], _a2, o2 + 4);                                            \
    }

#define ATTN_OY(OY, ST, SM, SB)                                                     \
    {                                                                               \
        floatx2 cf2[8];                                                             \
        {                                                                           \
            uint4 c0 = wlo[SM][1], c1 = whi[SM][1];                                 \
            cf2[0] = bf2f2(c0.x); cf2[1] = bf2f2(c0.y);                             \
            cf2[2] = bf2f2(c0.z); cf2[3] = bf2f2(c0.w);                             \
            cf2[4] = bf2f2(c1.x); cf2[5] = bf2f2(c1.y);                             \
            cf2[6] = bf2f2(c1.z); cf2[7] = bf2f2(c1.w);                             \
        }                                                                           \
        float s[9];                                                                 \
        s[0] = SCORE1(ST, 0); s[1] = SCORE1(ST, 1); s[2] = SCORE1(ST, 2);           \
        s[3] = SCORE1(SM, 0); s[4] = SCORE1(SM, 1); s[5] = SCORE1(SM, 2);           \
        s[6] = SCORE1(SB, 0); s[7] = SCORE1(SB, 1); s[8] = SCORE1(SB, 2);           \
        _Pragma("unroll")                                                           \
        for (int n = 0; n < 9; ++n)                                                 \
            s[n] = gsum8(s[n]) * 0.08838834764831845f;  /* 1/sqrt(128) */           \
        float m = s[0];                                                             \
        _Pragma("unroll")                                                           \
        for (int n = 1; n < 9; ++n) m = fmaxf(m, s[n]);                             \
        float e[9], sum = 0.f;                                                      \
        _Pragma("unroll")                                                           \
        for (int n = 0; n < 9; ++n) { e[n] = __expf(s[n] - m); sum += e[n]; }       \
        floatx2 o2[8];                                                              \
        _Pragma("unroll")                                                           \
        for (int k = 0; k < 8; ++k) { o2[k].x = 0.f; o2[k].y = 0.f; }               \
        PV(ST, 0, e[0]) PV(ST, 1, e[1]) PV(ST, 2, e[2])                             \
        PV(SM, 0, e[3]) PV(SM, 1, e[4]) PV(SM, 2, e[5])                             \
        PV(SB, 0, e[6]) PV(SB, 1, e[7]) PV(SB, 2, e[8])                             \
        float inv = 1.f / sum;                                                      \
        floatx2 inv2; inv2.x = inv; inv2.y = inv;                                   \
        float* og = out + ((size_t)((b * 128 + g * 16) * 128 + (h0 + (OY)))) * 128  \
                    + w0 + ox;                                                      \
        _Pragma("unroll")                                                           \
        for (int k = 0; k < 8; ++k) {                                               \
            floatx2 v = o2[k] * inv2;                                               \
            og[(2 * k) * 16384]     = v.x;                                          \
            og[(2 * k + 1) * 16384] = v.y;                                          \
        }                                                                           \
    }

__global__ __launch_bounds__(256, 2)
void attn_conv_fused(const float* __restrict__ x, const float* __restrict__ Wc,
                     const float* __restrict__ bc, float* __restrict__ out) {
    __shared__ __align__(16) unsigned char smem[34832];
    ushort* xs = (ushort*)smem;
    char* smc = (char*)smem;

    const int tid = threadIdx.x;
    // XCD-chunked swizzle (bijective, 2048 = 8*256): XCD k owns batch k entirely;
    // within an XCD, w-tiles fastest then h-bands -> halo rows stay L2-resident.
    const int rid = ((blockIdx.x & 7) << 8) | (blockIdx.x >> 3);
    const int b   = rid >> 8;
    const int h0  = ((rid >> 2) & 63) * 2;
    const int w0  = (rid & 3) * 32;
    const int lane = tid & 63;
    const int wv   = tid >> 6;

    // ---------------- Phase A0: stage x tile transposed -> xs[px][ci] bf16 ----
    if (tid < PXN) {
        int py  = (tid * 965) >> 15;          // tid / 34 (exact for tid<208)
        int pxx = tid - py * 34;
        int gh = h0 + py - 1, gw = w0 + pxx - 1;
        bool inb = (gh >= 0 && gh < 128 && gw >= 0 && gw < 128);
        ushort* dst = xs + tid * XS_STRIDE;
        if (inb) {
            const float* xp = x + (b * 64) * 16384 + gh * 128 + gw;
            #pragma unroll
            for (int c0 = 0; c0 < 64; c0 += 4) {
                float v0 = xp[(c0 + 0) << 14];
                float v1 = xp[(c0 + 1) << 14];
                float v2 = xp[(c0 + 2) << 14];
                float v3 = xp[(c0 + 3) << 14];
                unsigned int u01 = (unsigned int)f2bf(v0) | ((unsigned int)f2bf(v1) << 16);
                unsigned int u23 = (unsigned int)f2bf(v2) | ((unsigned int)f2bf(v3) << 16);
                *(uint2*)(dst + c0) = make_uint2(u01, u23);
            }
        } else {
            #pragma unroll
            for (int c0 = 0; c0 < 64; c0 += 4)
                *(uint2*)(dst + c0) = make_uint2(0u, 0u);
        }
    }

    // ---------------- Phase A1: W fragments (B-operand) from global ----------
    const int col = lane & 15;
    const int kq  = lane >> 4;
    short8 bw[8][2];
    float  bias[8];
    #pragma unroll
    for (int t = 0; t < 8; ++t) {
        int c = t * 16 + col;
        bias[t] = bc[c];
        #pragma unroll
        for (int half = 0; half < 2; ++half) {
            const float* wp = Wc + c * 64 + half * 32 + kq * 8;
            float4 wa = *(const float4*)wp;
            float4 wb = *(const float4*)(wp + 4);
            short8 f;
            f[0] = (short)f2bf(wa.x); f[1] = (short)f2bf(wa.y);
            f[2] = (short)f2bf(wa.z); f[3] = (short)f2bf(wa.w);
            f[4] = (short)f2bf(wb.x); f[5] = (short)f2bf(wb.y);
            f[6] = (short)f2bf(wb.z); f[7] = (short)f2bf(wb.w);
            bw[t][half] = f;
        }
    }
    __syncthreads();

    // ---------------- Phase A2a: preload this wave's A-fragments (xs dies) ----
    // 9 m-tiles (144 >= 136) over 4 waves: wave wv handles mt = wv, wv+4, wv+8
    short8 af0[3], af1[3];
    #pragma unroll
    for (int i = 0; i < 3; ++i) {
        int mt = wv + i * 4;
        if (mt < 9) {
            const ushort* ap = xs + (mt * 16 + col) * XS_STRIDE + kq * 8;
            af0[i] = *(const short8*)(ap);        // k 0..31  (px>=136 reads junk; masked on write)
            af1[i] = *(const short8*)(ap + 32);   // k 32..63
        }
    }
    __syncthreads();   // all xs reads done; P/Q (overlaying xs) now writable

    // ---------------- Phase A2b: MFMA conv -> P/Q bf16 (swizzled) ------------
    // channel c = t*16+col -> region (col<8 ? P : Q), chunk t ^ (pxr&7), slot col&7
    char* wbase = smc + (col < 8 ? 0 : QBASE);
    const int cb2 = (col & 7) * 2;
    #pragma unroll
    for (int i = 0; i < 3; ++i) {
        int mt = wv + i * 4;
        if (mt < 9) {
            floatx4 acc[8];
            #pragma unroll
            for (int t = 0; t < 8; ++t) acc[t] = (floatx4){0.f, 0.f, 0.f, 0.f};
            #pragma unroll
            for (int t = 0; t < 8; ++t) {
                acc[t] = __builtin_amdgcn_mfma_f32_16x16x32_bf16(af0[i], bw[t][0], acc[t], 0, 0, 0);
                acc[t] = __builtin_amdgcn_mfma_f32_16x16x32_bf16(af1[i], bw[t][1], acc[t], 0, 0, 0);
            }
            #pragma unroll
            for (int r = 0; r < 4; ++r) {
                int pxr = mt * 16 + kq * 4 + r;   // D row = (lane>>4)*4 + r
                if (pxr < PXN) {
                    int py  = (pxr * 965) >> 15;
                    int pxx = pxr - py * 34;
                    int gh = h0 + py - 1, gw = w0 + pxx - 1;
                    bool inb = (gh >= 0 && gh < 128 && gw >= 0 && gw < 128);
                    char* prow = wbase + pxr * 128;
                    int swz = (pxr & 7) << 4;
                    #pragma unroll
                    for (int t = 0; t < 8; ++t)
                        *(ushort*)(prow + (((t * 16) ^ swz) + cb2)) =
                            f2bf(inb ? (acc[t][r] + bias[t]) : 0.f);
                }
            }
        }
    }
    __syncthreads();   // LAST barrier: phase B is read-only on LDS, fully async

    // ---------------- Phase B: 3x3 local attention, barrier-free -------------
    // thread (g, ox): channels g*16..+15, pixel column ox; patch window carried
    // in registers across oy (rows oy..oy+2 of padded tile; reuse 2 of 3 rows).
    const int g  = tid & 7;                   // channel group: c0 = g*16
    const int ox = tid >> 3;                  // 0..31
    uint4 wlo[3][3], whi[3][3];               // [row slot][dx], lo=P chunk, hi=Q chunk

    LOADROW(0, 0) LOADROW(1, 1) LOADROW(2, 2)
    ATTN_OY(0, 0, 1, 2)
    LOADROW(0, 3)
    ATTN_OY(1, 1, 2, 0)
}

extern "C" void kernel_launch(void* const* d_in, const int* in_sizes, int n_in,
                              void* d_out, int out_size, void* d_ws, size_t ws_size,
                              hipStream_t stream) {
    const float* x  = (const float*)d_in[0];
    const float* Wc = (const float*)d_in[1];
    const float* bc = (const float*)d_in[2];
    float* out = (float*)d_out;

    dim3 grid(2048);         // flat; XCD-chunked decode in-kernel (h=2, w=32 tiles)
    dim3 block(256);
    attn_conv_fused<<<grid, block, 0, stream>>>(x, Wc, bc, out);
}

// Round 8
// 121.749 us; speedup vs baseline: 2.4755x; 1.1709x over previous
//
#include <hip/hip_runtime.h>
#include <hip/hip_fp16.h>

typedef __attribute__((ext_vector_type(8))) _Float16 half8; // 8 x f16 (4 VGPRs, MFMA A/B)
typedef __attribute__((ext_vector_type(2))) _Float16 h2v;   // packed f16 pair (1 VGPR)
typedef __attribute__((ext_vector_type(4))) float floatx4;  // MFMA acc

#define XS_STRIDE 72    // ushorts; xs[204][72] = 29376 B at smem+0, DEAD after A2a reg-preload
#define PXN 204         // staged pixels: 6 rows x 34 (h=4 tile + halo)
#define QBASE 26128     // Q region at 26112+16: +16 staggers Q bank quads by 1 vs P
// LDS map (52,240 B total -> 3 blocks/CU):  [round-5 geometry, best measured: 50 us]
//   P region [204][128B] at 0      : chunk g = channels g*16..+7 (f16), overlays xs
//   Q region [204][128B] at 26128  : chunk g = channels g*16+8..+15
//   chunk swizzle: physical 16B-chunk = logical ^ (px & 7)
// Phase B is BARRIER-FREE: direct per-channel stores; waves complete each 128B
// output line in L2 (verified round 5: WRITE_SIZE == output size exactly).
// DTYPE NOTE (round 8): Y staged as f16, not bf16. Scores use v_dot2_f32_f16
// (raw packed halves, no unpack); PV uses fma_mix (f16 src folded into FMA).
// This removes the ~144 bf16-unpack VALU ops per thread per oy (~50% of phase-B math).
// LAUNCH BOUNDS (measured r3-r6): (256,2) -> VGPR cap 128, no spill; 2nd arg 3 -> cap 84,
// 2nd arg 4 -> cap 64 = total spill (446 MB scratch). DO NOT raise the 2nd arg.

__device__ __forceinline__ ushort f2h(float f) {
    union { _Float16 h; ushort u; } cv;
    cv.h = (_Float16)f;
    return cv.u;
}
__device__ __forceinline__ h2v as_h2(unsigned int u) {
    union { unsigned int u; h2v h; } cv;
    cv.u = u;
    return cv.h;
}

// 8-lane (same-pixel) reduce: xor1/xor2 on VALU via DPP quad_perm, xor4 via shfl.
__device__ __forceinline__ float gsum8(float v) {
    v += __int_as_float(__builtin_amdgcn_update_dpp(0, __float_as_int(v), 0xB1, 0xF, 0xF, false)); // xor1
    v += __int_as_float(__builtin_amdgcn_update_dpp(0, __float_as_int(v), 0x4E, 0xF, 0xF, false)); // xor2
    v += __shfl_xor(v, 4);                                                                          // xor4
    return v;
}

// ---- phase-B building blocks (macros: compile-time slot indices -> registers) ----
#define LOADROW(S, PROW)                                                            \
    {                                                                               \
        _Pragma("unroll")                                                           \
        for (int dx = 0; dx < 3; ++dx) {                                            \
            int pi = (PROW) * 34 + ox + dx;                                         \
            const char* pp = smc + pi * 128 + ((g * 16) ^ ((pi & 7) << 4));         \
            wlo[S][dx] = *(const uint4*)pp;                                         \
            whi[S][dx] = *(const uint4*)(pp + QBASE);                               \
        }                                                                           \
    }

// score: 8 x v_dot2_f32_f16 per direction, split lo/hi accumulators (halved chain)
#define SCORE1(S, DX) ({                                                            \
        uint4 _l = wlo[S][DX], _h = whi[S][DX];                                     \
        float _s0 = 0.f, _s1 = 0.f;                                                 \
        _s0 = __builtin_amdgcn_fdot2(as_h2(_l.x), cfl[0], _s0, false);              \
        _s1 = __builtin_amdgcn_fdot2(as_h2(_l.y), cfl[1], _s1, false);              \
        _s0 = __builtin_amdgcn_fdot2(as_h2(_l.z), cfl[2], _s0, false);              \
        _s1 = __builtin_amdgcn_fdot2(as_h2(_l.w), cfl[3], _s1, false);              \
        _s0 = __builtin_amdgcn_fdot2(as_h2(_h.x), cfh[0], _s0, false);              \
        _s1 = __builtin_amdgcn_fdot2(as_h2(_h.y), cfh[1], _s1, false);              \
        _s0 = __builtin_amdgcn_fdot2(as_h2(_h.z), cfh[2], _s0, false);              \
        _s1 = __builtin_amdgcn_fdot2(as_h2(_h.w), cfh[3], _s1, false);              \
        _s0 + _s1; })

// PV: fmaf(half2float(x), a, o) pattern-fuses to v_fma_mix_f32 (no separate cvt)
#define PVU(U, A, O0, O1)                                                           \
    { h2v _v = as_h2(U);                                                            \
      O0 = fmaf((float)_v.x, (A), O0); O1 = fmaf((float)_v.y, (A), O1); }
#define PV(S, DX, A)                                                                \
    {                                                                               \
        uint4 _pl = wlo[S][DX], _ph = whi[S][DX];                                   \
        PVU(_pl.x, A, o[0], o[1])  PVU(_pl.y, A, o[2], o[3])                        \
        PVU(_pl.z, A, o[4], o[5])  PVU(_pl.w, A, o[6], o[7])                        \
        PVU(_ph.x, A, o[8], o[9])  PVU(_ph.y, A, o[10], o[11])                      \
        PVU(_ph.z, A, o[12], o[13]) PVU(_ph.w, A, o[14], o[15])                     \
    }

#define ATTN_OY(OY, ST, SM, SB)                                                     \
    {                                                                               \
        h2v cfl[4], cfh[4];                                                         \
        {                                                                           \
            uint4 c0 = wlo[SM][1], c1 = whi[SM][1];                                 \
            cfl[0] = as_h2(c0.x); cfl[1] = as_h2(c0.y);                             \
            cfl[2] = as_h2(c0.z); cfl[3] = as_h2(c0.w);                             \
            cfh[0] = as_h2(c1.x); cfh[1] = as_h2(c1.y);                             \
            cfh[2] = as_h2(c1.z); cfh[3] = as_h2(c1.w);                             \
        }                                                                           \
        float s[9];                                                                 \
        s[0] = SCORE1(ST, 0); s[1] = SCORE1(ST, 1); s[2] = SCORE1(ST, 2);           \
        s[3] = SCORE1(SM, 0); s[4] = SCORE1(SM, 1); s[5] = SCORE1(SM, 2);           \
        s[6] = SCORE1(SB, 0); s[7] = SCORE1(SB, 1); s[8] = SCORE1(SB, 2);           \
        _Pragma("unroll")                                                           \
        for (int n = 0; n < 9; ++n)                                                 \
            s[n] = gsum8(s[n]) * 0.08838834764831845f;  /* 1/sqrt(128) */           \
        float m = fmaxf(fmaxf(fmaxf(fmaxf(s[0], s[1]), s[2]),       /* v_max3 */    \
                              fmaxf(fmaxf(s[3], s[4]), s[5])),                      \
                        fmaxf(fmaxf(s[6], s[7]), s[8]));                            \
        float e[9], sum = 0.f;                                                      \
        _Pragma("unroll")                                                           \
        for (int n = 0; n < 9; ++n) { e[n] = __expf(s[n] - m); sum += e[n]; }       \
        float o[16];                                                                \
        _Pragma("unroll")                                                           \
        for (int j = 0; j < 16; ++j) o[j] = 0.f;                                    \
        PV(ST, 0, e[0]) PV(ST, 1, e[1]) PV(ST, 2, e[2])                             \
        PV(SM, 0, e[3]) PV(SM, 1, e[4]) PV(SM, 2, e[5])                             \
        PV(SB, 0, e[6]) PV(SB, 1, e[7]) PV(SB, 2, e[8])                             \
        float inv = 1.f / sum;                                                      \
        float* og = out + ((size_t)((b * 128 + g * 16) * 128 + (h0 + (OY)))) * 128  \
                    + w0 + ox;                                                      \
        _Pragma("unroll")                                                           \
        for (int j = 0; j < 16; ++j)                                                \
            og[j * 16384] = o[j] * inv;                                             \
    }

__global__ __launch_bounds__(256, 2)
void attn_conv_fused(const float* __restrict__ x, const float* __restrict__ Wc,
                     const float* __restrict__ bc, float* __restrict__ out) {
    __shared__ __align__(16) unsigned char smem[52240];
    ushort* xs = (ushort*)smem;
    char* smc = (char*)smem;

    const int tid = threadIdx.x;
    // XCD-chunked swizzle (bijective, 1024 = 8*128): XCD k owns batch k entirely;
    // within an XCD, w-tiles fastest then h-bands -> halo rows stay L2-resident.
    const int rid = ((blockIdx.x & 7) << 7) | (blockIdx.x >> 3);
    const int b   = rid >> 7;
    const int h0  = ((rid >> 2) & 31) * 4;
    const int w0  = (rid & 3) * 32;
    const int lane = tid & 63;
    const int wv   = tid >> 6;

    // ---------------- Phase A0: stage x tile transposed -> xs[px][ci] f16 -----
    if (tid < PXN) {
        int py  = (tid * 965) >> 15;          // tid / 34 (exact for tid<208)
        int pxx = tid - py * 34;
        int gh = h0 + py - 1, gw = w0 + pxx - 1;
        bool inb = (gh >= 0 && gh < 128 && gw >= 0 && gw < 128);
        ushort* dst = xs + tid * XS_STRIDE;
        if (inb) {
            const float* xp = x + (b * 64) * 16384 + gh * 128 + gw;
            #pragma unroll
            for (int c0 = 0; c0 < 64; c0 += 4) {
                float v0 = xp[(c0 + 0) << 14];
                float v1 = xp[(c0 + 1) << 14];
                float v2 = xp[(c0 + 2) << 14];
                float v3 = xp[(c0 + 3) << 14];
                unsigned int u01 = (unsigned int)f2h(v0) | ((unsigned int)f2h(v1) << 16);
                unsigned int u23 = (unsigned int)f2h(v2) | ((unsigned int)f2h(v3) << 16);
                *(uint2*)(dst + c0) = make_uint2(u01, u23);
            }
        } else {
            #pragma unroll
            for (int c0 = 0; c0 < 64; c0 += 4)
                *(uint2*)(dst + c0) = make_uint2(0u, 0u);
        }
    }

    // ---------------- Phase A1: W fragments (B-operand) from global ----------
    const int col = lane & 15;
    const int kq  = lane >> 4;
    half8 bw[8][2];
    float bias[8];
    #pragma unroll
    for (int t = 0; t < 8; ++t) {
        int c = t * 16 + col;
        bias[t] = bc[c];
        #pragma unroll
        for (int half = 0; half < 2; ++half) {
            const float* wp = Wc + c * 64 + half * 32 + kq * 8;
            float4 wa = *(const float4*)wp;
            float4 wb = *(const float4*)(wp + 4);
            half8 f;
            f[0] = (_Float16)wa.x; f[1] = (_Float16)wa.y;
            f[2] = (_Float16)wa.z; f[3] = (_Float16)wa.w;
            f[4] = (_Float16)wb.x; f[5] = (_Float16)wb.y;
            f[6] = (_Float16)wb.z; f[7] = (_Float16)wb.w;
            bw[t][half] = f;
        }
    }
    __syncthreads();

    // ---------------- Phase A2a: preload this wave's A-fragments (xs dies) ----
    half8 af0[4], af1[4];
    #pragma unroll
    for (int i = 0; i < 4; ++i) {
        int mt = wv + i * 4;
        if (mt < 13) {
            const ushort* ap = xs + (mt * 16 + col) * XS_STRIDE + kq * 8;
            af0[i] = *(const half8*)(ap);         // k 0..31
            af1[i] = *(const half8*)(ap + 32);    // k 32..63
        }
    }
    __syncthreads();   // all xs reads done; P/Q (overlaying xs) now writable

    // ---------------- Phase A2b: MFMA conv -> P/Q f16 (swizzled) -------------
    // channel c = t*16+col -> region (col<8 ? P : Q), chunk t ^ (pxr&7), slot col&7
    char* wbase = smc + (col < 8 ? 0 : QBASE);
    const int cb2 = (col & 7) * 2;
    #pragma unroll
    for (int i = 0; i < 4; ++i) {
        int mt = wv + i * 4;
        if (mt < 13) {
            floatx4 acc[8];
            #pragma unroll
            for (int t = 0; t < 8; ++t) acc[t] = (floatx4){0.f, 0.f, 0.f, 0.f};
            #pragma unroll
            for (int t = 0; t < 8; ++t) {
                acc[t] = __builtin_amdgcn_mfma_f32_16x16x32_f16(af0[i], bw[t][0], acc[t], 0, 0, 0);
                acc[t] = __builtin_amdgcn_mfma_f32_16x16x32_f16(af1[i], bw[t][1], acc[t], 0, 0, 0);
            }
            #pragma unroll
            for (int r = 0; r < 4; ++r) {
                int pxr = mt * 16 + kq * 4 + r;   // D row = (lane>>4)*4 + r
                if (pxr < PXN) {
                    int py  = (pxr * 965) >> 15;
                    int pxx = pxr - py * 34;
                    int gh = h0 + py - 1, gw = w0 + pxx - 1;
                    bool inb = (gh >= 0 && gh < 128 && gw >= 0 && gw < 128);
                    char* prow = wbase + pxr * 128;
                    int swz = (pxr & 7) << 4;
                    #pragma unroll
                    for (int t = 0; t < 8; ++t)
                        *(ushort*)(prow + (((t * 16) ^ swz) + cb2)) =
                            f2h(inb ? (acc[t][r] + bias[t]) : 0.f);
                }
            }
        }
    }
    __syncthreads();   // LAST barrier: phase B is read-only on LDS, fully async

    // ---------------- Phase B: 3x3 local attention, barrier-free -------------
    // thread (g, ox): channels g*16..+15, pixel column ox; patch window carried
    // in registers across oy (rows oy..oy+2 of padded tile; reuse 2 of 3 rows).
    const int g  = tid & 7;                   // channel group: c0 = g*16
    const int ox = tid >> 3;                  // 0..31
    uint4 wlo[3][3], whi[3][3];               // [row slot][dx], lo=P chunk, hi=Q chunk

    LOADROW(0, 0) LOADROW(1, 1) LOADROW(2, 2)
    ATTN_OY(0, 0, 1, 2)
    LOADROW(0, 3)
    ATTN_OY(1, 1, 2, 0)
    LOADROW(1, 4)
    ATTN_OY(2, 2, 0, 1)
    LOADROW(2, 5)
    ATTN_OY(3, 0, 1, 2)
}

extern "C" void kernel_launch(void* const* d_in, const int* in_sizes, int n_in,
                              void* d_out, int out_size, void* d_ws, size_t ws_size,
                              hipStream_t stream) {
    const float* x  = (const float*)d_in[0];
    const float* Wc = (const float*)d_in[1];
    const float* bc = (const float*)d_in[2];
    float* out = (float*)d_out;

    dim3 grid(1024);         // flat; XCD-chunked decode in-kernel (h=4, w=32 tiles)
    dim3 block(256);
    attn_conv_fused<<<grid, block, 0, stream>>>(x, Wc, bc, out);
}